// Round 9
// baseline (129.448 us; speedup 1.0000x reference)
//
#include <hip/hip_runtime.h>
#include <hip/hip_bf16.h>
#include <math.h>

// QANet Context-Query attention. B=32 H=128 C=2048 Q=256.
// R8: store Eb = bf16(exp(S)) instead of row-normalized RNb; row normalization
//     moves to out_mfma's epilogue (x rowinv). T2 staging = masked u16 copy
//     (no mul/cvt), T2 A-operand = ctxB bf16 (restored in prep_c).
//     colZ_j = sum_i cmask_i * Eb_ij (unchanged identity, exp-free).

constexpr int kB = 32, kH = 128, kC = 2048, kQ = 256;
constexpr int kColChunks = 128;          // (kC/64) blocks * 4 waves
constexpr float kNEG = -1e30f;

typedef short bf16x8 __attribute__((ext_vector_type(8)));
typedef float f32x4 __attribute__((ext_vector_type(4)));

static __device__ __forceinline__ unsigned short f2bf(float f) {
    __hip_bfloat16 h = __float2bfloat16(f);
    return __builtin_bit_cast(unsigned short, h);
}

// One ctx read -> ctxW[b,i,h]=bf16(ctx*w_cq), ctxB[b,h,i]=bf16(ctx), part_c.
__global__ __launch_bounds__(256) void k_prep_c(const float* __restrict__ ctx,
                                                const float* __restrict__ w_c,
                                                const float* __restrict__ w_cq,
                                                unsigned short* __restrict__ ctxW,
                                                unsigned short* __restrict__ ctxB,
                                                float* __restrict__ part_c) {
    int i0 = blockIdx.x * 64, b = blockIdx.y;
    __shared__ unsigned short tile[64 * 136];
    __shared__ float pcp[4][64];
    int t = threadIdx.x;
    int il = t & 63, hg = t >> 6, hb = hg * 2;
    float accc = 0.f;
#pragma unroll
    for (int r = 0; r < 16; ++r) {
        int h = r * 8 + hb;
        float v0 = ctx[((size_t)b * kH + h) * kC + i0 + il];
        float v1 = ctx[((size_t)b * kH + h + 1) * kC + i0 + il];
        accc += v0 * w_c[h] + v1 * w_c[h + 1];
        ctxB[((size_t)b * kH + h) * kC + i0 + il]     = f2bf(v0);
        ctxB[((size_t)b * kH + h + 1) * kC + i0 + il] = f2bf(v1);
        unsigned int pk = (unsigned int)f2bf(v0 * w_cq[h]) |
                          ((unsigned int)f2bf(v1 * w_cq[h + 1]) << 16);
        *(unsigned int*)&tile[il * 136 + h] = pk;
    }
    pcp[hg][il] = accc;
    __syncthreads();
    if (t < 64) part_c[b * kC + i0 + t] = pcp[0][t] + pcp[1][t] + pcp[2][t] + pcp[3][t];
#pragma unroll
    for (int r = 0; r < 4; ++r) {
        int idx = r * 256 + t;
        int i = idx >> 4, hc = (idx & 15) * 8;
        *(bf16x8*)&ctxW[((size_t)b * kC + i0 + i) * kH + hc] =
            *(const bf16x8*)&tile[i * 136 + hc];
    }
}

// One q read -> qT[b,j,h]=bf16(q), qB[b,h,j]=bf16(q), part_q.
__global__ __launch_bounds__(256) void k_prep_q(const float* __restrict__ q,
                                                const float* __restrict__ w_q,
                                                unsigned short* __restrict__ qT,
                                                unsigned short* __restrict__ qB,
                                                float* __restrict__ part_q) {
    int j0 = blockIdx.x * 64, b = blockIdx.y;
    __shared__ unsigned short tile[64 * 136];
    __shared__ float pcp[4][64];
    int t = threadIdx.x;
    int jl = t & 63, hg = t >> 6, hb = hg * 2;
    float accq = 0.f;
#pragma unroll
    for (int r = 0; r < 16; ++r) {
        int h = r * 8 + hb;
        float v0 = q[((size_t)b * kH + h) * kQ + j0 + jl];
        float v1 = q[((size_t)b * kH + h + 1) * kQ + j0 + jl];
        accq += v0 * w_q[h] + v1 * w_q[h + 1];
        qB[((size_t)b * kH + h) * kQ + j0 + jl]     = f2bf(v0);
        qB[((size_t)b * kH + h + 1) * kQ + j0 + jl] = f2bf(v1);
        unsigned int pk = (unsigned int)f2bf(v0) | ((unsigned int)f2bf(v1) << 16);
        *(unsigned int*)&tile[jl * 136 + h] = pk;
    }
    pcp[hg][jl] = accq;
    __syncthreads();
    if (t < 64) part_q[b * kQ + j0 + t] = pcp[0][t] + pcp[1][t] + pcp[2][t] + pcp[3][t];
#pragma unroll
    for (int r = 0; r < 4; ++r) {
        int idx = r * 256 + t;
        int j = idx >> 4, hc = (idx & 15) * 8;
        *(bf16x8*)&qT[((size_t)b * kQ + j0 + j) * kH + hc] =
            *(const bf16x8*)&tile[j * 136 + hc];
    }
}

// Fused S + softmax. Block = 64 i x 256 j; wave = 16 i x 256 j.
// Writes Eb = bf16(exp(S)) (qmasked), rowinv = 1/sum_j exp(S), and column
// partial sums cs_j = sum_{i in chunk, cmask} exp(S_ij).
__global__ __launch_bounds__(256) void k_Ssoft(const unsigned short* __restrict__ ctxW,
                                               const unsigned short* __restrict__ qT,
                                               const float* __restrict__ part_c,
                                               const float* __restrict__ part_q,
                                               const float* __restrict__ bias,
                                               const int* __restrict__ qmask,
                                               const int* __restrict__ cmask,
                                               unsigned short* __restrict__ Eb,
                                               float* __restrict__ rowinv,
                                               float* __restrict__ ps) {
    int i0 = blockIdx.x * 64, b = blockIdx.y;
    __shared__ unsigned short As[64 * 40];
    __shared__ unsigned short Bs[256 * 40];
    __shared__ float smpq[256];
    __shared__ int smqm[256];
    int t = threadIdx.x;
    int lane = t & 63, w = t >> 6;
    int lrow = lane & 15, q4 = lane >> 4, kgrp = q4 * 8;
    smpq[t] = part_q[b * kQ + t];
    smqm[t] = qmask[b * kQ + t];

    f32x4 acc[16];
#pragma unroll
    for (int nt = 0; nt < 16; ++nt) acc[nt] = (f32x4){0.f, 0.f, 0.f, 0.f};

    for (int kk = 0; kk < 4; ++kk) {
        int h0 = kk * 32;
        {
            int iA = t >> 2, hcA = (t & 3) * 8;
            *(bf16x8*)&As[iA * 40 + hcA] =
                *(const bf16x8*)&ctxW[((size_t)b * kC + i0 + iA) * kH + h0 + hcA];
        }
#pragma unroll
        for (int r2 = 0; r2 < 4; ++r2) {
            int idx = r2 * 256 + t;
            int jB = idx >> 2, hcB = (idx & 3) * 8;
            *(bf16x8*)&Bs[jB * 40 + hcB] =
                *(const bf16x8*)&qT[((size_t)b * kQ + jB) * kH + h0 + hcB];
        }
        __syncthreads();
        bf16x8 af = *(const bf16x8*)&As[(w * 16 + lrow) * 40 + kgrp];
#pragma unroll
        for (int nt = 0; nt < 16; ++nt) {
            bf16x8 bf = *(const bf16x8*)&Bs[(nt * 16 + lrow) * 40 + kgrp];
            acc[nt] = __builtin_amdgcn_mfma_f32_16x16x32_bf16(af, bf, acc[nt], 0, 0, 0);
        }
        __syncthreads();
    }

    // ---- epilogue: parts + row softmax (E + rowinv) + column partial sums ----
    float bs = bias[0];
    float pq[16];
    int qm[16];
#pragma unroll
    for (int nt = 0; nt < 16; ++nt) {
        int col = nt * 16 + lrow;
        pq[nt] = smpq[col];
        qm[nt] = smqm[col];
    }
    int rowbase = i0 + w * 16 + q4 * 4;
    float pc[4];
    int cmr[4];
#pragma unroll
    for (int r = 0; r < 4; ++r) {
        pc[r] = part_c[b * kC + rowbase + r] + bs;
        cmr[r] = cmask[b * kC + rowbase + r];
    }
#pragma unroll
    for (int nt = 0; nt < 16; ++nt)
#pragma unroll
        for (int r = 0; r < 4; ++r)
            acc[nt][r] += pc[r] + pq[nt];

    float cs[16];
#pragma unroll
    for (int nt = 0; nt < 16; ++nt) cs[nt] = 0.f;

#pragma unroll
    for (int r = 0; r < 4; ++r) {
        float rmax = kNEG;
#pragma unroll
        for (int nt = 0; nt < 16; ++nt)
            if (qm[nt]) rmax = fmaxf(rmax, acc[nt][r]);
        rmax = fmaxf(rmax, __shfl_xor(rmax, 1));
        rmax = fmaxf(rmax, __shfl_xor(rmax, 2));
        rmax = fmaxf(rmax, __shfl_xor(rmax, 4));
        rmax = fmaxf(rmax, __shfl_xor(rmax, 8));
        float e[16];
        float rsum = 0.f;
#pragma unroll
        for (int nt = 0; nt < 16; ++nt) {
            e[nt] = qm[nt] ? __expf(acc[nt][r] - rmax) : 0.f;
            rsum += e[nt];
        }
        rsum += __shfl_xor(rsum, 1);
        rsum += __shfl_xor(rsum, 2);
        rsum += __shfl_xor(rsum, 4);
        rsum += __shfl_xor(rsum, 8);
        float emax = __expf(rmax);
        float Z = rsum * emax;                 // = sum_j exp(S_ij)
        unsigned short* dst = Eb + ((size_t)b * kC + rowbase + r) * kQ;
#pragma unroll
        for (int nt = 0; nt < 16; ++nt)
            dst[nt * 16 + lrow] = f2bf(e[nt] * emax);   // = exp(S_ij)
        if (lrow == 0)
            rowinv[b * kC + rowbase + r] = Z > 0.f ? 1.f / Z : 0.f;
        if (cmr[r]) {
#pragma unroll
            for (int nt = 0; nt < 16; ++nt)
                cs[nt] += e[nt] * emax;
        }
    }
    // plain-sum combine across the 4 lane-quarters (different rows, same cols)
#pragma unroll
    for (int nt = 0; nt < 16; ++nt) {
        cs[nt] += __shfl_xor(cs[nt], 16);
        cs[nt] += __shfl_xor(cs[nt], 32);
    }
    int chunk = blockIdx.x * 4 + w;
#pragma unroll
    for (int k = 0; k < 4; ++k) {
        int nt = q4 * 4 + k;
        int col = nt * 16 + lrow;
        ps[((size_t)b * kColChunks + chunk) * kQ + col] = cs[nt];
    }
}

// colinv = 1/colZ (0 if colZ==0: fully-masked column, harmless downstream).
__global__ __launch_bounds__(256) void k_colZ(const float* __restrict__ ps,
                                              float* __restrict__ colinv) {
    int id = blockIdx.x * 256 + threadIdx.x;   // over B*Q
    int b = id / kQ, j = id % kQ;
    float s = 0.f;
#pragma unroll 8
    for (int c = 0; c < kColChunks; ++c)
        s += ps[((size_t)b * kColChunks + c) * kQ + j];
    colinv[id] = s > 0.f ? 1.f / s : 0.f;
}

// T partials via MFMA. B-operand = (cmask ? Eb : 0)^T staged transposed
// (pure u16 select-copy); A = ctxB bf16 (direct copy).
__global__ __launch_bounds__(256) void k_T2_mfma(const unsigned short* __restrict__ Eb,
                                                 const unsigned short* __restrict__ ctxB,
                                                 const int* __restrict__ cmask,
                                                 float* __restrict__ Tpart) {
    int chunk = blockIdx.x, jt = blockIdx.y, b = blockIdx.z;
    int j0 = jt * 128;
    __shared__ unsigned short Et[128 * 40];   // [j][i] transposed E tile
    __shared__ unsigned short Bs[128 * 40];   // [h][i] ctx bf16
    __shared__ int smc[256];
    int t = threadIdx.x;
    smc[t] = cmask[b * kC + chunk * 256 + t];
    int lane = t & 63, wave = t >> 6;
    int wm = wave >> 1, wn = wave & 1;
    int lrow = lane & 15, kgrp = (lane >> 4) * 8;
    int ip = t >> 4, js = t & 15;
    int hB = t >> 1, isegB = (t & 1) * 16;

    f32x4 acc[4][4];
#pragma unroll
    for (int mt = 0; mt < 4; ++mt)
#pragma unroll
        for (int nt = 0; nt < 4; ++nt)
            acc[mt][nt] = (f32x4){0.f, 0.f, 0.f, 0.f};
    __syncthreads();

    for (int kk = 0; kk < 8; ++kk) {
        int i0 = chunk * 256 + kk * 32;
        int li = kk * 32 + 2 * ip;
        unsigned int m0 = smc[li]     ? 0xFFFFu : 0u;
        unsigned int m1 = smc[li + 1] ? 0xFFFFu : 0u;
        const unsigned short* r0 = Eb + ((size_t)b * kC + i0 + 2 * ip) * kQ + j0;
#pragma unroll
        for (int m = 0; m < 8; ++m) {
            int j = js + 16 * m;
            unsigned int e0 = (unsigned int)r0[j] & m0;
            unsigned int e1 = (unsigned int)r0[kQ + j] & m1;
            *(unsigned int*)&Et[j * 40 + 2 * ip] = e0 | (e1 << 16);
        }
        {
            const unsigned short* cb = ctxB + ((size_t)b * kH + hB) * kC + i0 + isegB;
            *(bf16x8*)&Bs[hB * 40 + isegB]     = *(const bf16x8*)cb;
            *(bf16x8*)&Bs[hB * 40 + isegB + 8] = *(const bf16x8*)(cb + 8);
        }
        __syncthreads();
        bf16x8 af[4], bfr[4];
#pragma unroll
        for (int mt = 0; mt < 4; ++mt)
            af[mt] = *(const bf16x8*)&Bs[(wm * 64 + mt * 16 + lrow) * 40 + kgrp];
#pragma unroll
        for (int nt = 0; nt < 4; ++nt)
            bfr[nt] = *(const bf16x8*)&Et[(wn * 64 + nt * 16 + lrow) * 40 + kgrp];
#pragma unroll
        for (int nt = 0; nt < 4; ++nt)
#pragma unroll
            for (int mt = 0; mt < 4; ++mt)
                acc[mt][nt] = __builtin_amdgcn_mfma_f32_16x16x32_bf16(af[mt], bfr[nt], acc[mt][nt], 0, 0, 0);
        __syncthreads();
    }

    const size_t M = (size_t)kB * kH * kQ;
#pragma unroll
    for (int mt = 0; mt < 4; ++mt)
#pragma unroll
        for (int r = 0; r < 4; ++r) {
            int h = wm * 64 + mt * 16 + (lane >> 4) * 4 + r;
            float* dst = Tpart + (size_t)chunk * M + ((size_t)b * kH + h) * kQ + j0 + wn * 64 + lrow;
#pragma unroll
            for (int nt = 0; nt < 4; ++nt)
                dst[nt * 16] = acc[mt][nt][r];
        }
}

// T_bf16[b,h,j] = bf16( colinv[b,j] * sum_chunk Tpart[chunk][b,h,j] )
__global__ __launch_bounds__(256) void k_Tred(const float* __restrict__ Tpart,
                                              const float* __restrict__ colinv,
                                              unsigned short* __restrict__ Tb) {
    size_t id = (size_t)blockIdx.x * 256 + threadIdx.x;   // over B*H*Q
    const size_t M = (size_t)kB * kH * kQ;
    int j = (int)(id % kQ);
    int b = (int)(id / ((size_t)kH * kQ));
    float s = 0.f;
#pragma unroll
    for (int c = 0; c < 8; ++c) s += Tpart[c * M + id];
    Tb[id] = f2bf(s * colinv[b * kQ + j]);
}

// Output kernel: 64 i x 128 h per block. A = Eb via LDS; B fragments (qB/Tb)
// direct from global (L2-hot). Epilogue: x rowinv (row normalization), one ctx
// read serves all four outputs.
__global__ __launch_bounds__(256) void k_out_mfma(const unsigned short* __restrict__ Eb,
                                                  const unsigned short* __restrict__ qB,
                                                  const unsigned short* __restrict__ Tb,
                                                  const float* __restrict__ ctx,
                                                  const float* __restrict__ rowinv,
                                                  float* __restrict__ out) {
    int i0 = blockIdx.x * 64;
    int b  = blockIdx.y;
    __shared__ unsigned short As[64 * 40];
    __shared__ float stgC[64 * 68];
    __shared__ float stgT[64 * 68];
    int t = threadIdx.x;
    int rA = t >> 2, cA = (t & 3) * 8;
    int lane = t & 63, wave = t >> 6;
    int hw = wave * 32;
    int kgrp = (lane >> 4) * 8;
    int lrow = lane & 15, q4 = lane >> 4;

    f32x4 accC[4][2];
    f32x4 accT[4][2];
#pragma unroll
    for (int mt = 0; mt < 4; ++mt)
#pragma unroll
        for (int nt = 0; nt < 2; ++nt) {
            accC[mt][nt] = (f32x4){0.f, 0.f, 0.f, 0.f};
            accT[mt][nt] = (f32x4){0.f, 0.f, 0.f, 0.f};
        }

    for (int kk = 0; kk < 8; ++kk) {
        int j0 = kk * 32;
        *(bf16x8*)&As[rA * 40 + cA] =
            *(const bf16x8*)&Eb[((size_t)b * kC + i0 + rA) * kQ + j0 + cA];
        __syncthreads();
        bf16x8 af[4];
#pragma unroll
        for (int mt = 0; mt < 4; ++mt)
            af[mt] = *(const bf16x8*)&As[(mt * 16 + lrow) * 40 + kgrp];
#pragma unroll
        for (int nt = 0; nt < 2; ++nt) {
            int h = hw + nt * 16 + lrow;
            bf16x8 bq = *(const bf16x8*)&qB[((size_t)b * kH + h) * kQ + j0 + kgrp];
            bf16x8 bt = *(const bf16x8*)&Tb[((size_t)b * kH + h) * kQ + j0 + kgrp];
#pragma unroll
            for (int mt = 0; mt < 4; ++mt) {
                accC[mt][nt] = __builtin_amdgcn_mfma_f32_16x16x32_bf16(af[mt], bq, accC[mt][nt], 0, 0, 0);
                accT[mt][nt] = __builtin_amdgcn_mfma_f32_16x16x32_bf16(af[mt], bt, accT[mt][nt], 0, 0, 0);
            }
        }
        __syncthreads();
    }

    const size_t N = (size_t)kB * kH * kC;
    int ii = t & 63, hb = t >> 6;
    float riv = rowinv[b * kC + i0 + ii];
#pragma unroll
    for (int g = 0; g < 2; ++g) {
        if ((wave >> 1) == g) {
            int hloc = (wave & 1) * 32;
#pragma unroll
            for (int mt = 0; mt < 4; ++mt)
#pragma unroll
                for (int nt = 0; nt < 2; ++nt)
#pragma unroll
                    for (int r = 0; r < 4; ++r) {
                        int rowh = hloc + nt * 16 + lrow;
                        int coli = mt * 16 + q4 * 4 + r;
                        stgC[rowh * 68 + coli] = accC[mt][nt][r];
                        stgT[rowh * 68 + coli] = accT[mt][nt][r];
                    }
        }
        __syncthreads();
#pragma unroll 4
        for (int p = 0; p < 16; ++p) {
            int hl = hb + p * 4;
            int h = g * 64 + hl;
            float vc = stgC[hl * 68 + ii] * riv;
            float vt = stgT[hl * 68 + ii] * riv;
            size_t base = ((size_t)b * kH + h) * kC + i0 + ii;
            float c = ctx[base];
            out[base]         = c;
            out[N + base]     = vc;
            out[2 * N + base] = c * vc;
            out[3 * N + base] = c * vt;
        }
        __syncthreads();
    }
}

extern "C" void kernel_launch(void* const* d_in, const int* in_sizes, int n_in,
                              void* d_out, int out_size, void* d_ws, size_t ws_size,
                              hipStream_t stream) {
    const float* ctx   = (const float*)d_in[0];
    const float* q     = (const float*)d_in[1];
    const int*   cmask = (const int*)d_in[2];
    const int*   qmask = (const int*)d_in[3];
    const float* w_c   = (const float*)d_in[4];
    const float* w_q   = (const float*)d_in[5];
    const float* w_cq  = (const float*)d_in[6];
    const float* bias  = (const float*)d_in[7];
    float* out = (float*)d_out;

    // Workspace (~60 MB of 512 MiB).
    unsigned short* Eb   = (unsigned short*)d_ws;                 // B*C*Q bf16
    unsigned short* ctxB = Eb + (size_t)kB * kC * kQ;             // B*H*C bf16
    unsigned short* qB   = ctxB + (size_t)kB * kH * kC;           // B*H*Q bf16
    unsigned short* Tb   = qB + (size_t)kB * kH * kQ;             // B*H*Q bf16
    float* part_c = (float*)(Tb + (size_t)kB * kH * kQ);          // B*C
    float* part_q = part_c + kB * kC;                             // B*Q
    float* rowinv = part_q + kB * kQ;                             // B*C
    float* colinv = rowinv + kB * kC;                             // B*Q
    float* ps     = colinv + kB * kQ;                             // B*128*Q
    size_t need = (size_t)((char*)(ps + (size_t)kB * kColChunks * kQ) - (char*)d_ws);
    if (ws_size < need) return;

    // d_out scratch (consumed before k_out_mfma writes):
    //   [0, N) floats      : Tpart (8 * B*H*Q f32)
    //   [2N, 2.5N) floats  : ctxW (B*C*H bf16)
    //   then qT            : (B*Q*H bf16)
    const size_t N = (size_t)kB * kH * kC;
    float* Tpart = out;
    unsigned short* ctxW = (unsigned short*)(out + 2 * N);
    unsigned short* qT   = ctxW + (size_t)kB * kC * kH;

    k_prep_c<<<dim3(kC / 64, kB), 256, 0, stream>>>(ctx, w_c, w_cq, ctxW, ctxB, part_c);
    k_prep_q<<<dim3(kQ / 64, kB), 256, 0, stream>>>(q, w_q, qT, qB, part_q);
    k_Ssoft<<<dim3(kC / 64, kB), 256, 0, stream>>>(ctxW, qT, part_c, part_q, bias,
                                                   qmask, cmask, Eb, rowinv, ps);
    k_colZ<<<kB * kQ / 256, 256, 0, stream>>>(ps, colinv);
    k_T2_mfma<<<dim3(8, 2, kB), 256, 0, stream>>>(Eb, ctxB, cmask, Tpart);
    k_Tred<<<kB * kH * kQ / 256, 256, 0, stream>>>(Tpart, colinv, Tb);
    k_out_mfma<<<dim3(kC / 64, kB), 256, 0, stream>>>(Eb, qB, Tb, ctx, rowinv, out);
}

// Round 10
// 114.277 us; speedup vs baseline: 1.1328x; 1.1328x over previous
//
#include <hip/hip_runtime.h>
#include <hip/hip_bf16.h>
#include <math.h>

// QANet Context-Query attention. B=32 H=128 C=2048 Q=256.
// R9: revert R8's ctxB (net traffic loss: +33.5MB write to save ~17MB reads);
//     T2 A-operand back to fp32-ctx staging (R7 form). Keep Eb=exp(S),
//     exp-free colZ, masked-u16 Et staging, rowinv-in-epilogue. NEW: Tpart
//     stored bf16 (fp32 in-register, one rounding) -> -33.5MB traffic.

constexpr int kB = 32, kH = 128, kC = 2048, kQ = 256;
constexpr int kColChunks = 128;          // (kC/64) blocks * 4 waves
constexpr float kNEG = -1e30f;

typedef short bf16x8 __attribute__((ext_vector_type(8)));
typedef float f32x4 __attribute__((ext_vector_type(4)));

static __device__ __forceinline__ unsigned short f2bf(float f) {
    __hip_bfloat16 h = __float2bfloat16(f);
    return __builtin_bit_cast(unsigned short, h);
}
static __device__ __forceinline__ float bf2f(unsigned short u) {
    unsigned int x = ((unsigned int)u) << 16;
    return __builtin_bit_cast(float, x);
}

// One ctx read -> ctxW[b,i,h]=bf16(ctx*w_cq) and part_c.
__global__ __launch_bounds__(256) void k_prep_c(const float* __restrict__ ctx,
                                                const float* __restrict__ w_c,
                                                const float* __restrict__ w_cq,
                                                unsigned short* __restrict__ ctxW,
                                                float* __restrict__ part_c) {
    int i0 = blockIdx.x * 64, b = blockIdx.y;
    __shared__ unsigned short tile[64 * 136];
    __shared__ float pcp[4][64];
    int t = threadIdx.x;
    int il = t & 63, hg = t >> 6, hb = hg * 2;
    float accc = 0.f;
#pragma unroll
    for (int r = 0; r < 16; ++r) {
        int h = r * 8 + hb;
        float v0 = ctx[((size_t)b * kH + h) * kC + i0 + il];
        float v1 = ctx[((size_t)b * kH + h + 1) * kC + i0 + il];
        accc += v0 * w_c[h] + v1 * w_c[h + 1];
        unsigned int pk = (unsigned int)f2bf(v0 * w_cq[h]) |
                          ((unsigned int)f2bf(v1 * w_cq[h + 1]) << 16);
        *(unsigned int*)&tile[il * 136 + h] = pk;
    }
    pcp[hg][il] = accc;
    __syncthreads();
    if (t < 64) part_c[b * kC + i0 + t] = pcp[0][t] + pcp[1][t] + pcp[2][t] + pcp[3][t];
#pragma unroll
    for (int r = 0; r < 4; ++r) {
        int idx = r * 256 + t;
        int i = idx >> 4, hc = (idx & 15) * 8;
        *(bf16x8*)&ctxW[((size_t)b * kC + i0 + i) * kH + hc] =
            *(const bf16x8*)&tile[i * 136 + hc];
    }
}

// One q read -> qT[b,j,h]=bf16(q), qB[b,h,j]=bf16(q), part_q.
__global__ __launch_bounds__(256) void k_prep_q(const float* __restrict__ q,
                                                const float* __restrict__ w_q,
                                                unsigned short* __restrict__ qT,
                                                unsigned short* __restrict__ qB,
                                                float* __restrict__ part_q) {
    int j0 = blockIdx.x * 64, b = blockIdx.y;
    __shared__ unsigned short tile[64 * 136];
    __shared__ float pcp[4][64];
    int t = threadIdx.x;
    int jl = t & 63, hg = t >> 6, hb = hg * 2;
    float accq = 0.f;
#pragma unroll
    for (int r = 0; r < 16; ++r) {
        int h = r * 8 + hb;
        float v0 = q[((size_t)b * kH + h) * kQ + j0 + jl];
        float v1 = q[((size_t)b * kH + h + 1) * kQ + j0 + jl];
        accq += v0 * w_q[h] + v1 * w_q[h + 1];
        qB[((size_t)b * kH + h) * kQ + j0 + jl]     = f2bf(v0);
        qB[((size_t)b * kH + h + 1) * kQ + j0 + jl] = f2bf(v1);
        unsigned int pk = (unsigned int)f2bf(v0) | ((unsigned int)f2bf(v1) << 16);
        *(unsigned int*)&tile[jl * 136 + h] = pk;
    }
    pcp[hg][jl] = accq;
    __syncthreads();
    if (t < 64) part_q[b * kQ + j0 + t] = pcp[0][t] + pcp[1][t] + pcp[2][t] + pcp[3][t];
#pragma unroll
    for (int r = 0; r < 4; ++r) {
        int idx = r * 256 + t;
        int j = idx >> 4, hc = (idx & 15) * 8;
        *(bf16x8*)&qT[((size_t)b * kQ + j0 + j) * kH + hc] =
            *(const bf16x8*)&tile[j * 136 + hc];
    }
}

// Fused S + softmax. Block = 64 i x 256 j; wave = 16 i x 256 j.
// Writes Eb = bf16(exp(S)) (qmasked), rowinv = 1/sum_j exp(S), and column
// partial sums cs_j = sum_{i in chunk, cmask} exp(S_ij).
__global__ __launch_bounds__(256) void k_Ssoft(const unsigned short* __restrict__ ctxW,
                                               const unsigned short* __restrict__ qT,
                                               const float* __restrict__ part_c,
                                               const float* __restrict__ part_q,
                                               const float* __restrict__ bias,
                                               const int* __restrict__ qmask,
                                               const int* __restrict__ cmask,
                                               unsigned short* __restrict__ Eb,
                                               float* __restrict__ rowinv,
                                               float* __restrict__ ps) {
    int i0 = blockIdx.x * 64, b = blockIdx.y;
    __shared__ unsigned short As[64 * 40];
    __shared__ unsigned short Bs[256 * 40];
    __shared__ float smpq[256];
    __shared__ int smqm[256];
    int t = threadIdx.x;
    int lane = t & 63, w = t >> 6;
    int lrow = lane & 15, q4 = lane >> 4, kgrp = q4 * 8;
    smpq[t] = part_q[b * kQ + t];
    smqm[t] = qmask[b * kQ + t];

    f32x4 acc[16];
#pragma unroll
    for (int nt = 0; nt < 16; ++nt) acc[nt] = (f32x4){0.f, 0.f, 0.f, 0.f};

    for (int kk = 0; kk < 4; ++kk) {
        int h0 = kk * 32;
        {
            int iA = t >> 2, hcA = (t & 3) * 8;
            *(bf16x8*)&As[iA * 40 + hcA] =
                *(const bf16x8*)&ctxW[((size_t)b * kC + i0 + iA) * kH + h0 + hcA];
        }
#pragma unroll
        for (int r2 = 0; r2 < 4; ++r2) {
            int idx = r2 * 256 + t;
            int jB = idx >> 2, hcB = (idx & 3) * 8;
            *(bf16x8*)&Bs[jB * 40 + hcB] =
                *(const bf16x8*)&qT[((size_t)b * kQ + jB) * kH + h0 + hcB];
        }
        __syncthreads();
        bf16x8 af = *(const bf16x8*)&As[(w * 16 + lrow) * 40 + kgrp];
#pragma unroll
        for (int nt = 0; nt < 16; ++nt) {
            bf16x8 bf = *(const bf16x8*)&Bs[(nt * 16 + lrow) * 40 + kgrp];
            acc[nt] = __builtin_amdgcn_mfma_f32_16x16x32_bf16(af, bf, acc[nt], 0, 0, 0);
        }
        __syncthreads();
    }

    // ---- epilogue: parts + row softmax (E + rowinv) + column partial sums ----
    float bs = bias[0];
    float pq[16];
    int qm[16];
#pragma unroll
    for (int nt = 0; nt < 16; ++nt) {
        int col = nt * 16 + lrow;
        pq[nt] = smpq[col];
        qm[nt] = smqm[col];
    }
    int rowbase = i0 + w * 16 + q4 * 4;
    float pc[4];
    int cmr[4];
#pragma unroll
    for (int r = 0; r < 4; ++r) {
        pc[r] = part_c[b * kC + rowbase + r] + bs;
        cmr[r] = cmask[b * kC + rowbase + r];
    }
#pragma unroll
    for (int nt = 0; nt < 16; ++nt)
#pragma unroll
        for (int r = 0; r < 4; ++r)
            acc[nt][r] += pc[r] + pq[nt];

    float cs[16];
#pragma unroll
    for (int nt = 0; nt < 16; ++nt) cs[nt] = 0.f;

#pragma unroll
    for (int r = 0; r < 4; ++r) {
        float rmax = kNEG;
#pragma unroll
        for (int nt = 0; nt < 16; ++nt)
            if (qm[nt]) rmax = fmaxf(rmax, acc[nt][r]);
        rmax = fmaxf(rmax, __shfl_xor(rmax, 1));
        rmax = fmaxf(rmax, __shfl_xor(rmax, 2));
        rmax = fmaxf(rmax, __shfl_xor(rmax, 4));
        rmax = fmaxf(rmax, __shfl_xor(rmax, 8));
        float e[16];
        float rsum = 0.f;
#pragma unroll
        for (int nt = 0; nt < 16; ++nt) {
            e[nt] = qm[nt] ? __expf(acc[nt][r] - rmax) : 0.f;
            rsum += e[nt];
        }
        rsum += __shfl_xor(rsum, 1);
        rsum += __shfl_xor(rsum, 2);
        rsum += __shfl_xor(rsum, 4);
        rsum += __shfl_xor(rsum, 8);
        float emax = __expf(rmax);
        float Z = rsum * emax;                 // = sum_j exp(S_ij)
        unsigned short* dst = Eb + ((size_t)b * kC + rowbase + r) * kQ;
#pragma unroll
        for (int nt = 0; nt < 16; ++nt)
            dst[nt * 16 + lrow] = f2bf(e[nt] * emax);   // = exp(S_ij)
        if (lrow == 0)
            rowinv[b * kC + rowbase + r] = Z > 0.f ? 1.f / Z : 0.f;
        if (cmr[r]) {
#pragma unroll
            for (int nt = 0; nt < 16; ++nt)
                cs[nt] += e[nt] * emax;
        }
    }
    // plain-sum combine across the 4 lane-quarters (different rows, same cols)
#pragma unroll
    for (int nt = 0; nt < 16; ++nt) {
        cs[nt] += __shfl_xor(cs[nt], 16);
        cs[nt] += __shfl_xor(cs[nt], 32);
    }
    int chunk = blockIdx.x * 4 + w;
#pragma unroll
    for (int k = 0; k < 4; ++k) {
        int nt = q4 * 4 + k;
        int col = nt * 16 + lrow;
        ps[((size_t)b * kColChunks + chunk) * kQ + col] = cs[nt];
    }
}

// colinv = 1/colZ (0 if colZ==0: fully-masked column, harmless downstream).
__global__ __launch_bounds__(256) void k_colZ(const float* __restrict__ ps,
                                              float* __restrict__ colinv) {
    int id = blockIdx.x * 256 + threadIdx.x;   // over B*Q
    int b = id / kQ, j = id % kQ;
    float s = 0.f;
#pragma unroll 8
    for (int c = 0; c < kColChunks; ++c)
        s += ps[((size_t)b * kColChunks + c) * kQ + j];
    colinv[id] = s > 0.f ? 1.f / s : 0.f;
}

// T partials via MFMA. B-operand = (cmask ? Eb : 0)^T staged transposed
// (pure u16 select-copy); A = ctx fp32 staged -> bf16. Tpart stored bf16.
__global__ __launch_bounds__(256) void k_T2_mfma(const unsigned short* __restrict__ Eb,
                                                 const float* __restrict__ ctx,
                                                 const int* __restrict__ cmask,
                                                 unsigned short* __restrict__ Tpart) {
    int chunk = blockIdx.x, jt = blockIdx.y, b = blockIdx.z;
    int j0 = jt * 128;
    __shared__ unsigned short Et[128 * 40];   // [j][i] transposed E tile
    __shared__ unsigned short Bs[128 * 40];   // [h][i] ctx bf16
    __shared__ int smc[256];
    int t = threadIdx.x;
    smc[t] = cmask[b * kC + chunk * 256 + t];
    int lane = t & 63, wave = t >> 6;
    int wm = wave >> 1, wn = wave & 1;
    int lrow = lane & 15, kgrp = (lane >> 4) * 8;
    int ip = t >> 4, js = t & 15;
    int hB = t >> 1, isegB = (t & 1) * 16;

    f32x4 acc[4][4];
#pragma unroll
    for (int mt = 0; mt < 4; ++mt)
#pragma unroll
        for (int nt = 0; nt < 4; ++nt)
            acc[mt][nt] = (f32x4){0.f, 0.f, 0.f, 0.f};
    __syncthreads();

    for (int kk = 0; kk < 8; ++kk) {
        int i0 = chunk * 256 + kk * 32;
        int li = kk * 32 + 2 * ip;
        unsigned int m0 = smc[li]     ? 0xFFFFu : 0u;
        unsigned int m1 = smc[li + 1] ? 0xFFFFu : 0u;
        const unsigned short* r0 = Eb + ((size_t)b * kC + i0 + 2 * ip) * kQ + j0;
#pragma unroll
        for (int m = 0; m < 8; ++m) {
            int j = js + 16 * m;
            unsigned int e0 = (unsigned int)r0[j] & m0;
            unsigned int e1 = (unsigned int)r0[kQ + j] & m1;
            *(unsigned int*)&Et[j * 40 + 2 * ip] = e0 | (e1 << 16);
        }
        {   // A: ctx fp32 -> bf16, rows h, 32-i segment
            const float* cb = ctx + ((size_t)b * kH + hB) * kC + i0 + isegB;
            float4 a0 = *(const float4*)cb;
            float4 a1 = *(const float4*)(cb + 4);
            float4 a2 = *(const float4*)(cb + 8);
            float4 a3 = *(const float4*)(cb + 12);
            float vv[16] = {a0.x, a0.y, a0.z, a0.w, a1.x, a1.y, a1.z, a1.w,
                            a2.x, a2.y, a2.z, a2.w, a3.x, a3.y, a3.z, a3.w};
            bf16x8 p0, p1;
#pragma unroll
            for (int e = 0; e < 8; ++e) {
                p0[e] = (short)f2bf(vv[e]);
                p1[e] = (short)f2bf(vv[8 + e]);
            }
            *(bf16x8*)&Bs[hB * 40 + isegB]     = p0;
            *(bf16x8*)&Bs[hB * 40 + isegB + 8] = p1;
        }
        __syncthreads();
        bf16x8 af[4], bfr[4];
#pragma unroll
        for (int mt = 0; mt < 4; ++mt)
            af[mt] = *(const bf16x8*)&Bs[(wm * 64 + mt * 16 + lrow) * 40 + kgrp];
#pragma unroll
        for (int nt = 0; nt < 4; ++nt)
            bfr[nt] = *(const bf16x8*)&Et[(wn * 64 + nt * 16 + lrow) * 40 + kgrp];
#pragma unroll
        for (int nt = 0; nt < 4; ++nt)
#pragma unroll
            for (int mt = 0; mt < 4; ++mt)
                acc[mt][nt] = __builtin_amdgcn_mfma_f32_16x16x32_bf16(af[mt], bfr[nt], acc[mt][nt], 0, 0, 0);
        __syncthreads();
    }

    const size_t M = (size_t)kB * kH * kQ;
#pragma unroll
    for (int mt = 0; mt < 4; ++mt)
#pragma unroll
        for (int r = 0; r < 4; ++r) {
            int h = wm * 64 + mt * 16 + (lane >> 4) * 4 + r;
            unsigned short* dst = Tpart + (size_t)chunk * M + ((size_t)b * kH + h) * kQ + j0 + wn * 64 + lrow;
#pragma unroll
            for (int nt = 0; nt < 4; ++nt)
                dst[nt * 16] = f2bf(acc[mt][nt][r]);
        }
}

// T_bf16[b,h,j] = bf16( colinv[b,j] * sum_chunk bf2f(Tpart[chunk][b,h,j]) )
__global__ __launch_bounds__(256) void k_Tred(const unsigned short* __restrict__ Tpart,
                                              const float* __restrict__ colinv,
                                              unsigned short* __restrict__ Tb) {
    size_t id = (size_t)blockIdx.x * 256 + threadIdx.x;   // over B*H*Q
    const size_t M = (size_t)kB * kH * kQ;
    int j = (int)(id % kQ);
    int b = (int)(id / ((size_t)kH * kQ));
    float s = 0.f;
#pragma unroll
    for (int c = 0; c < 8; ++c) s += bf2f(Tpart[c * M + id]);
    Tb[id] = f2bf(s * colinv[b * kQ + j]);
}

// Output kernel: 64 i x 128 h per block. A = Eb via LDS; B fragments (qB/Tb)
// direct from global (L2-hot). Epilogue: x rowinv (row normalization), one ctx
// read serves all four outputs.
__global__ __launch_bounds__(256) void k_out_mfma(const unsigned short* __restrict__ Eb,
                                                  const unsigned short* __restrict__ qB,
                                                  const unsigned short* __restrict__ Tb,
                                                  const float* __restrict__ ctx,
                                                  const float* __restrict__ rowinv,
                                                  float* __restrict__ out) {
    int i0 = blockIdx.x * 64;
    int b  = blockIdx.y;
    __shared__ unsigned short As[64 * 40];
    __shared__ float stgC[64 * 68];
    __shared__ float stgT[64 * 68];
    int t = threadIdx.x;
    int rA = t >> 2, cA = (t & 3) * 8;
    int lane = t & 63, wave = t >> 6;
    int hw = wave * 32;
    int kgrp = (lane >> 4) * 8;
    int lrow = lane & 15, q4 = lane >> 4;

    f32x4 accC[4][2];
    f32x4 accT[4][2];
#pragma unroll
    for (int mt = 0; mt < 4; ++mt)
#pragma unroll
        for (int nt = 0; nt < 2; ++nt) {
            accC[mt][nt] = (f32x4){0.f, 0.f, 0.f, 0.f};
            accT[mt][nt] = (f32x4){0.f, 0.f, 0.f, 0.f};
        }

    for (int kk = 0; kk < 8; ++kk) {
        int j0 = kk * 32;
        *(bf16x8*)&As[rA * 40 + cA] =
            *(const bf16x8*)&Eb[((size_t)b * kC + i0 + rA) * kQ + j0 + cA];
        __syncthreads();
        bf16x8 af[4];
#pragma unroll
        for (int mt = 0; mt < 4; ++mt)
            af[mt] = *(const bf16x8*)&As[(mt * 16 + lrow) * 40 + kgrp];
#pragma unroll
        for (int nt = 0; nt < 2; ++nt) {
            int h = hw + nt * 16 + lrow;
            bf16x8 bq = *(const bf16x8*)&qB[((size_t)b * kH + h) * kQ + j0 + kgrp];
            bf16x8 bt = *(const bf16x8*)&Tb[((size_t)b * kH + h) * kQ + j0 + kgrp];
#pragma unroll
            for (int mt = 0; mt < 4; ++mt) {
                accC[mt][nt] = __builtin_amdgcn_mfma_f32_16x16x32_bf16(af[mt], bq, accC[mt][nt], 0, 0, 0);
                accT[mt][nt] = __builtin_amdgcn_mfma_f32_16x16x32_bf16(af[mt], bt, accT[mt][nt], 0, 0, 0);
            }
        }
        __syncthreads();
    }

    const size_t N = (size_t)kB * kH * kC;
    int ii = t & 63, hb = t >> 6;
    float riv = rowinv[b * kC + i0 + ii];
#pragma unroll
    for (int g = 0; g < 2; ++g) {
        if ((wave >> 1) == g) {
            int hloc = (wave & 1) * 32;
#pragma unroll
            for (int mt = 0; mt < 4; ++mt)
#pragma unroll
                for (int nt = 0; nt < 2; ++nt)
#pragma unroll
                    for (int r = 0; r < 4; ++r) {
                        int rowh = hloc + nt * 16 + lrow;
                        int coli = mt * 16 + q4 * 4 + r;
                        stgC[rowh * 68 + coli] = accC[mt][nt][r];
                        stgT[rowh * 68 + coli] = accT[mt][nt][r];
                    }
        }
        __syncthreads();
#pragma unroll 4
        for (int p = 0; p < 16; ++p) {
            int hl = hb + p * 4;
            int h = g * 64 + hl;
            float vc = stgC[hl * 68 + ii] * riv;
            float vt = stgT[hl * 68 + ii] * riv;
            size_t base = ((size_t)b * kH + h) * kC + i0 + ii;
            float c = ctx[base];
            out[base]         = c;
            out[N + base]     = vc;
            out[2 * N + base] = c * vc;
            out[3 * N + base] = c * vt;
        }
        __syncthreads();
    }
}

extern "C" void kernel_launch(void* const* d_in, const int* in_sizes, int n_in,
                              void* d_out, int out_size, void* d_ws, size_t ws_size,
                              hipStream_t stream) {
    const float* ctx   = (const float*)d_in[0];
    const float* q     = (const float*)d_in[1];
    const int*   cmask = (const int*)d_in[2];
    const int*   qmask = (const int*)d_in[3];
    const float* w_c   = (const float*)d_in[4];
    const float* w_q   = (const float*)d_in[5];
    const float* w_cq  = (const float*)d_in[6];
    const float* bias  = (const float*)d_in[7];
    float* out = (float*)d_out;

    // Workspace (~42 MB of 512 MiB).
    unsigned short* Eb = (unsigned short*)d_ws;                   // B*C*Q bf16
    unsigned short* qB = Eb + (size_t)kB * kC * kQ;               // B*H*Q bf16
    unsigned short* Tb = qB + (size_t)kB * kH * kQ;               // B*H*Q bf16
    float* part_c = (float*)(Tb + (size_t)kB * kH * kQ);          // B*C
    float* part_q = part_c + kB * kC;                             // B*Q
    float* rowinv = part_q + kB * kQ;                             // B*C
    float* colinv = rowinv + kB * kC;                             // B*Q
    float* ps     = colinv + kB * kQ;                             // B*128*Q
    size_t need = (size_t)((char*)(ps + (size_t)kB * kColChunks * kQ) - (char*)d_ws);
    if (ws_size < need) return;

    // d_out scratch (consumed before k_out_mfma writes):
    //   [0 ..)             : Tpart (8 * B*H*Q bf16 = 16.8 MB)
    //   [2N, 2.5N) floats  : ctxW (B*C*H bf16)
    //   then qT            : (B*Q*H bf16)
    const size_t N = (size_t)kB * kH * kC;
    unsigned short* Tpart = (unsigned short*)out;
    unsigned short* ctxW  = (unsigned short*)(out + 2 * N);
    unsigned short* qT    = ctxW + (size_t)kB * kC * kH;

    k_prep_c<<<dim3(kC / 64, kB), 256, 0, stream>>>(ctx, w_c, w_cq, ctxW, part_c);
    k_prep_q<<<dim3(kQ / 64, kB), 256, 0, stream>>>(q, w_q, qT, qB, part_q);
    k_Ssoft<<<dim3(kC / 64, kB), 256, 0, stream>>>(ctxW, qT, part_c, part_q, bias,
                                                   qmask, cmask, Eb, rowinv, ps);
    k_colZ<<<kB * kQ / 256, 256, 0, stream>>>(ps, colinv);
    k_T2_mfma<<<dim3(8, 2, kB), 256, 0, stream>>>(Eb, ctx, cmask, Tpart);
    k_Tred<<<kB * kH * kQ / 256, 256, 0, stream>>>(Tpart, colinv, Tb);
    k_out_mfma<<<dim3(kC / 64, kB), 256, 0, stream>>>(Eb, qB, Tb, ctx, rowinv, out);
}

// Round 11
// 110.754 us; speedup vs baseline: 1.1688x; 1.0318x over previous
//
#include <hip/hip_runtime.h>
#include <hip/hip_bf16.h>
#include <math.h>

// QANet Context-Query attention. B=32 H=128 C=2048 Q=256.
// R10: (1) prep_c/ctxW deleted -- Ssoft builds A-fragments direct from global
//      ctx (w_cq folded in-register) and computes part_c from the same loads.
//      (2) k_T2 merged to one 512-thr block per (chunk,b): ctx+Eb read once.
//      Keeps R9's Eb=exp(S), exp-free colZ, bf16 Tpart, rowinv-epilogue.

constexpr int kB = 32, kH = 128, kC = 2048, kQ = 256;
constexpr int kColChunks = 128;          // (kC/64) blocks * 4 waves
constexpr float kNEG = -1e30f;

typedef short bf16x8 __attribute__((ext_vector_type(8)));
typedef float f32x4 __attribute__((ext_vector_type(4)));

static __device__ __forceinline__ unsigned short f2bf(float f) {
    __hip_bfloat16 h = __float2bfloat16(f);
    return __builtin_bit_cast(unsigned short, h);
}
static __device__ __forceinline__ float bf2f(unsigned short u) {
    unsigned int x = ((unsigned int)u) << 16;
    return __builtin_bit_cast(float, x);
}

// One q read -> qT[b,j,h]=bf16(q), qB[b,h,j]=bf16(q), part_q.
__global__ __launch_bounds__(256) void k_prep_q(const float* __restrict__ q,
                                                const float* __restrict__ w_q,
                                                unsigned short* __restrict__ qT,
                                                unsigned short* __restrict__ qB,
                                                float* __restrict__ part_q) {
    int j0 = blockIdx.x * 64, b = blockIdx.y;
    __shared__ unsigned short tile[64 * 136];
    __shared__ float pcp[4][64];
    int t = threadIdx.x;
    int jl = t & 63, hg = t >> 6, hb = hg * 2;
    float accq = 0.f;
#pragma unroll
    for (int r = 0; r < 16; ++r) {
        int h = r * 8 + hb;
        float v0 = q[((size_t)b * kH + h) * kQ + j0 + jl];
        float v1 = q[((size_t)b * kH + h + 1) * kQ + j0 + jl];
        accq += v0 * w_q[h] + v1 * w_q[h + 1];
        qB[((size_t)b * kH + h) * kQ + j0 + jl]     = f2bf(v0);
        qB[((size_t)b * kH + h + 1) * kQ + j0 + jl] = f2bf(v1);
        unsigned int pk = (unsigned int)f2bf(v0) | ((unsigned int)f2bf(v1) << 16);
        *(unsigned int*)&tile[jl * 136 + h] = pk;
    }
    pcp[hg][jl] = accq;
    __syncthreads();
    if (t < 64) part_q[b * kQ + j0 + t] = pcp[0][t] + pcp[1][t] + pcp[2][t] + pcp[3][t];
#pragma unroll
    for (int r = 0; r < 4; ++r) {
        int idx = r * 256 + t;
        int j = idx >> 4, hc = (idx & 15) * 8;
        *(bf16x8*)&qT[((size_t)b * kQ + j0 + j) * kH + hc] =
            *(const bf16x8*)&tile[j * 136 + hc];
    }
}

// Fused S + softmax. Block = 64 i x 256 j; wave = 16 i x 256 j.
// A-fragments loaded DIRECT from global ctx (8 scalar fp32 loads/lane/step,
// w_cq folded at pack time); part_c accumulated from the same loads.
// Writes Eb = bf16(exp(S)) (qmasked), rowinv = 1/rowZ, col partial sums.
__global__ __launch_bounds__(256) void k_Ssoft(const float* __restrict__ ctx,
                                               const unsigned short* __restrict__ qT,
                                               const float* __restrict__ w_c,
                                               const float* __restrict__ w_cq,
                                               const float* __restrict__ part_q,
                                               const float* __restrict__ bias,
                                               const int* __restrict__ qmask,
                                               const int* __restrict__ cmask,
                                               unsigned short* __restrict__ Eb,
                                               float* __restrict__ rowinv,
                                               float* __restrict__ ps) {
    int i0 = blockIdx.x * 64, b = blockIdx.y;
    __shared__ unsigned short Bs[256 * 40];
    __shared__ float smpq[256];
    __shared__ int smqm[256];
    __shared__ float smwc[128];
    __shared__ float smwq[128];
    __shared__ float smpc[64];
    int t = threadIdx.x;
    int lane = t & 63, w = t >> 6;
    int lrow = lane & 15, q4 = lane >> 4, kgrp = q4 * 8;
    smpq[t] = part_q[b * kQ + t];
    smqm[t] = qmask[b * kQ + t];
    if (t < 128) smwc[t] = w_c[t];
    else smwq[t - 128] = w_cq[t - 128];
    __syncthreads();

    const float* cbase = ctx + (size_t)b * kH * kC + i0 + w * 16 + lrow;
    float pcl = 0.f;

    f32x4 acc[16];
#pragma unroll
    for (int nt = 0; nt < 16; ++nt) acc[nt] = (f32x4){0.f, 0.f, 0.f, 0.f};

#pragma unroll
    for (int kk = 0; kk < 4; ++kk) {
        int h0 = kk * 32;
        // A-fragment: direct global loads, w_cq fold, part_c accumulate
        bf16x8 af;
#pragma unroll
        for (int e = 0; e < 8; ++e) {
            int h = h0 + kgrp + e;
            float v = cbase[(size_t)h * kC];
            pcl += v * smwc[h];
            af[e] = (short)f2bf(v * smwq[h]);
        }
        // B staging from qT (K-contiguous bf16)
#pragma unroll
        for (int r2 = 0; r2 < 4; ++r2) {
            int idx = r2 * 256 + t;
            int jB = idx >> 2, hcB = (idx & 3) * 8;
            *(bf16x8*)&Bs[jB * 40 + hcB] =
                *(const bf16x8*)&qT[((size_t)b * kQ + jB) * kH + h0 + hcB];
        }
        __syncthreads();
#pragma unroll
        for (int nt = 0; nt < 16; ++nt) {
            bf16x8 bf = *(const bf16x8*)&Bs[(nt * 16 + lrow) * 40 + kgrp];
            acc[nt] = __builtin_amdgcn_mfma_f32_16x16x32_bf16(af, bf, acc[nt], 0, 0, 0);
        }
        __syncthreads();
    }

    // part_c: combine h-disjoint lane partials (same row i = w*16+lrow)
    pcl += __shfl_xor(pcl, 16);
    pcl += __shfl_xor(pcl, 32);
    if (q4 == 0) smpc[w * 16 + lrow] = pcl;
    __syncthreads();

    // ---- epilogue: parts + row softmax (E + rowinv) + column partial sums ----
    float bs = bias[0];
    float pq[16];
    int qm[16];
#pragma unroll
    for (int nt = 0; nt < 16; ++nt) {
        int col = nt * 16 + lrow;
        pq[nt] = smpq[col];
        qm[nt] = smqm[col];
    }
    int rowbase = i0 + w * 16 + q4 * 4;
    float pc[4];
    int cmr[4];
#pragma unroll
    for (int r = 0; r < 4; ++r) {
        pc[r] = smpc[w * 16 + q4 * 4 + r] + bs;
        cmr[r] = cmask[b * kC + rowbase + r];
    }
#pragma unroll
    for (int nt = 0; nt < 16; ++nt)
#pragma unroll
        for (int r = 0; r < 4; ++r)
            acc[nt][r] += pc[r] + pq[nt];

    float cs[16];
#pragma unroll
    for (int nt = 0; nt < 16; ++nt) cs[nt] = 0.f;

#pragma unroll
    for (int r = 0; r < 4; ++r) {
        float rmax = kNEG;
#pragma unroll
        for (int nt = 0; nt < 16; ++nt)
            if (qm[nt]) rmax = fmaxf(rmax, acc[nt][r]);
        rmax = fmaxf(rmax, __shfl_xor(rmax, 1));
        rmax = fmaxf(rmax, __shfl_xor(rmax, 2));
        rmax = fmaxf(rmax, __shfl_xor(rmax, 4));
        rmax = fmaxf(rmax, __shfl_xor(rmax, 8));
        float e[16];
        float rsum = 0.f;
#pragma unroll
        for (int nt = 0; nt < 16; ++nt) {
            e[nt] = qm[nt] ? __expf(acc[nt][r] - rmax) : 0.f;
            rsum += e[nt];
        }
        rsum += __shfl_xor(rsum, 1);
        rsum += __shfl_xor(rsum, 2);
        rsum += __shfl_xor(rsum, 4);
        rsum += __shfl_xor(rsum, 8);
        float emax = __expf(rmax);
        float Z = rsum * emax;                 // = sum_j exp(S_ij)
        unsigned short* dst = Eb + ((size_t)b * kC + rowbase + r) * kQ;
#pragma unroll
        for (int nt = 0; nt < 16; ++nt)
            dst[nt * 16 + lrow] = f2bf(e[nt] * emax);   // = exp(S_ij)
        if (lrow == 0)
            rowinv[b * kC + rowbase + r] = Z > 0.f ? 1.f / Z : 0.f;
        if (cmr[r]) {
#pragma unroll
            for (int nt = 0; nt < 16; ++nt)
                cs[nt] += e[nt] * emax;
        }
    }
    // plain-sum combine across the 4 lane-quarters (different rows, same cols)
#pragma unroll
    for (int nt = 0; nt < 16; ++nt) {
        cs[nt] += __shfl_xor(cs[nt], 16);
        cs[nt] += __shfl_xor(cs[nt], 32);
    }
    int chunk = blockIdx.x * 4 + w;
#pragma unroll
    for (int k = 0; k < 4; ++k) {
        int nt = q4 * 4 + k;
        int col = nt * 16 + lrow;
        ps[((size_t)b * kColChunks + chunk) * kQ + col] = cs[nt];
    }
}

// colinv = 1/colZ (0 if colZ==0: fully-masked column, harmless downstream).
__global__ __launch_bounds__(256) void k_colZ(const float* __restrict__ ps,
                                              float* __restrict__ colinv) {
    int id = blockIdx.x * 256 + threadIdx.x;   // over B*Q
    int b = id / kQ, j = id % kQ;
    float s = 0.f;
#pragma unroll 8
    for (int c = 0; c < kColChunks; ++c)
        s += ps[((size_t)b * kColChunks + c) * kQ + j];
    colinv[id] = s > 0.f ? 1.f / s : 0.f;
}

// T partials via MFMA. One 512-thr block per (chunk, b): 128 h x 256 j.
// Each ctx/Eb element read exactly once. 8 waves: wm=wave>>1 (32-h quarter),
// wn=wave&1 (128-j half); acc 2x8 f32x4. Tpart stored bf16.
__global__ __launch_bounds__(512) void k_T2_mfma(const unsigned short* __restrict__ Eb,
                                                 const float* __restrict__ ctx,
                                                 const int* __restrict__ cmask,
                                                 unsigned short* __restrict__ Tpart) {
    int chunk = blockIdx.x, b = blockIdx.y;
    __shared__ unsigned short Et[256 * 40];   // [j][i] transposed E tile
    __shared__ unsigned short Bs[128 * 40];   // [h][i] ctx bf16
    __shared__ int smc[256];
    int t = threadIdx.x;
    if (t < 256) smc[t] = cmask[b * kC + chunk * 256 + t];
    int lane = t & 63, wave = t >> 6;
    int wm = wave >> 1, wn = wave & 1;
    int lrow = lane & 15, kgrp = (lane >> 4) * 8;
    int ip = t >> 5, js = t & 31;
    int hB = t >> 2, isegB = (t & 3) * 8;

    f32x4 acc[2][8];
#pragma unroll
    for (int mt = 0; mt < 2; ++mt)
#pragma unroll
        for (int nt = 0; nt < 8; ++nt)
            acc[mt][nt] = (f32x4){0.f, 0.f, 0.f, 0.f};
    __syncthreads();

    for (int kk = 0; kk < 8; ++kk) {
        int i0 = chunk * 256 + kk * 32;
        int li = kk * 32 + 2 * ip;
        unsigned int m0 = smc[li]     ? 0xFFFFu : 0u;
        unsigned int m1 = smc[li + 1] ? 0xFFFFu : 0u;
        const unsigned short* r0 = Eb + ((size_t)b * kC + i0 + 2 * ip) * kQ;
#pragma unroll
        for (int m = 0; m < 8; ++m) {
            int j = js + 32 * m;
            unsigned int e0 = (unsigned int)r0[j] & m0;
            unsigned int e1 = (unsigned int)r0[kQ + j] & m1;
            *(unsigned int*)&Et[j * 40 + 2 * ip] = e0 | (e1 << 16);
        }
        {   // A: ctx fp32 -> bf16, row hB, 8-i segment
            const float* cb = ctx + ((size_t)b * kH + hB) * kC + i0 + isegB;
            float4 a0 = *(const float4*)cb;
            float4 a1 = *(const float4*)(cb + 4);
            float vv[8] = {a0.x, a0.y, a0.z, a0.w, a1.x, a1.y, a1.z, a1.w};
            bf16x8 p0;
#pragma unroll
            for (int e = 0; e < 8; ++e) p0[e] = (short)f2bf(vv[e]);
            *(bf16x8*)&Bs[hB * 40 + isegB] = p0;
        }
        __syncthreads();
        bf16x8 af[2], bfr[8];
#pragma unroll
        for (int mt = 0; mt < 2; ++mt)
            af[mt] = *(const bf16x8*)&Bs[(wm * 32 + mt * 16 + lrow) * 40 + kgrp];
#pragma unroll
        for (int nt = 0; nt < 8; ++nt)
            bfr[nt] = *(const bf16x8*)&Et[(wn * 128 + nt * 16 + lrow) * 40 + kgrp];
#pragma unroll
        for (int nt = 0; nt < 8; ++nt)
#pragma unroll
            for (int mt = 0; mt < 2; ++mt)
                acc[mt][nt] = __builtin_amdgcn_mfma_f32_16x16x32_bf16(af[mt], bfr[nt], acc[mt][nt], 0, 0, 0);
        __syncthreads();
    }

    const size_t M = (size_t)kB * kH * kQ;
#pragma unroll
    for (int mt = 0; mt < 2; ++mt)
#pragma unroll
        for (int r = 0; r < 4; ++r) {
            int h = wm * 32 + mt * 16 + (lane >> 4) * 4 + r;
            unsigned short* dst = Tpart + (size_t)chunk * M + ((size_t)b * kH + h) * kQ + wn * 128 + lrow;
#pragma unroll
            for (int nt = 0; nt < 8; ++nt)
                dst[nt * 16] = f2bf(acc[mt][nt][r]);
        }
}

// T_bf16[b,h,j] = bf16( colinv[b,j] * sum_chunk bf2f(Tpart[chunk][b,h,j]) )
__global__ __launch_bounds__(256) void k_Tred(const unsigned short* __restrict__ Tpart,
                                              const float* __restrict__ colinv,
                                              unsigned short* __restrict__ Tb) {
    size_t id = (size_t)blockIdx.x * 256 + threadIdx.x;   // over B*H*Q
    const size_t M = (size_t)kB * kH * kQ;
    int j = (int)(id % kQ);
    int b = (int)(id / ((size_t)kH * kQ));
    float s = 0.f;
#pragma unroll
    for (int c = 0; c < 8; ++c) s += bf2f(Tpart[c * M + id]);
    Tb[id] = f2bf(s * colinv[b * kQ + j]);
}

// Output kernel: 64 i x 128 h per block. A = Eb via LDS; B fragments (qB/Tb)
// direct from global (L2-hot). Epilogue: x rowinv, one ctx read, 4 outputs.
__global__ __launch_bounds__(256) void k_out_mfma(const unsigned short* __restrict__ Eb,
                                                  const unsigned short* __restrict__ qB,
                                                  const unsigned short* __restrict__ Tb,
                                                  const float* __restrict__ ctx,
                                                  const float* __restrict__ rowinv,
                                                  float* __restrict__ out) {
    int i0 = blockIdx.x * 64;
    int b  = blockIdx.y;
    __shared__ unsigned short As[64 * 40];
    __shared__ float stgC[64 * 68];
    __shared__ float stgT[64 * 68];
    int t = threadIdx.x;
    int rA = t >> 2, cA = (t & 3) * 8;
    int lane = t & 63, wave = t >> 6;
    int hw = wave * 32;
    int kgrp = (lane >> 4) * 8;
    int lrow = lane & 15, q4 = lane >> 4;

    f32x4 accC[4][2];
    f32x4 accT[4][2];
#pragma unroll
    for (int mt = 0; mt < 4; ++mt)
#pragma unroll
        for (int nt = 0; nt < 2; ++nt) {
            accC[mt][nt] = (f32x4){0.f, 0.f, 0.f, 0.f};
            accT[mt][nt] = (f32x4){0.f, 0.f, 0.f, 0.f};
        }

    for (int kk = 0; kk < 8; ++kk) {
        int j0 = kk * 32;
        *(bf16x8*)&As[rA * 40 + cA] =
            *(const bf16x8*)&Eb[((size_t)b * kC + i0 + rA) * kQ + j0 + cA];
        __syncthreads();
        bf16x8 af[4];
#pragma unroll
        for (int mt = 0; mt < 4; ++mt)
            af[mt] = *(const bf16x8*)&As[(mt * 16 + lrow) * 40 + kgrp];
#pragma unroll
        for (int nt = 0; nt < 2; ++nt) {
            int h = hw + nt * 16 + lrow;
            bf16x8 bq = *(const bf16x8*)&qB[((size_t)b * kH + h) * kQ + j0 + kgrp];
            bf16x8 bt = *(const bf16x8*)&Tb[((size_t)b * kH + h) * kQ + j0 + kgrp];
#pragma unroll
            for (int mt = 0; mt < 4; ++mt) {
                accC[mt][nt] = __builtin_amdgcn_mfma_f32_16x16x32_bf16(af[mt], bq, accC[mt][nt], 0, 0, 0);
                accT[mt][nt] = __builtin_amdgcn_mfma_f32_16x16x32_bf16(af[mt], bt, accT[mt][nt], 0, 0, 0);
            }
        }
        __syncthreads();
    }

    const size_t N = (size_t)kB * kH * kC;
    int ii = t & 63, hb = t >> 6;
    float riv = rowinv[b * kC + i0 + ii];
#pragma unroll
    for (int g = 0; g < 2; ++g) {
        if ((wave >> 1) == g) {
            int hloc = (wave & 1) * 32;
#pragma unroll
            for (int mt = 0; mt < 4; ++mt)
#pragma unroll
                for (int nt = 0; nt < 2; ++nt)
#pragma unroll
                    for (int r = 0; r < 4; ++r) {
                        int rowh = hloc + nt * 16 + lrow;
                        int coli = mt * 16 + q4 * 4 + r;
                        stgC[rowh * 68 + coli] = accC[mt][nt][r];
                        stgT[rowh * 68 + coli] = accT[mt][nt][r];
                    }
        }
        __syncthreads();
#pragma unroll 4
        for (int p = 0; p < 16; ++p) {
            int hl = hb + p * 4;
            int h = g * 64 + hl;
            float vc = stgC[hl * 68 + ii] * riv;
            float vt = stgT[hl * 68 + ii] * riv;
            size_t base = ((size_t)b * kH + h) * kC + i0 + ii;
            float c = ctx[base];
            out[base]         = c;
            out[N + base]     = vc;
            out[2 * N + base] = c * vc;
            out[3 * N + base] = c * vt;
        }
        __syncthreads();
    }
}

extern "C" void kernel_launch(void* const* d_in, const int* in_sizes, int n_in,
                              void* d_out, int out_size, void* d_ws, size_t ws_size,
                              hipStream_t stream) {
    const float* ctx   = (const float*)d_in[0];
    const float* q     = (const float*)d_in[1];
    const int*   cmask = (const int*)d_in[2];
    const int*   qmask = (const int*)d_in[3];
    const float* w_c   = (const float*)d_in[4];
    const float* w_q   = (const float*)d_in[5];
    const float* w_cq  = (const float*)d_in[6];
    const float* bias  = (const float*)d_in[7];
    float* out = (float*)d_out;

    // Workspace (~42 MB of 512 MiB).
    unsigned short* Eb = (unsigned short*)d_ws;                   // B*C*Q bf16
    unsigned short* qB = Eb + (size_t)kB * kC * kQ;               // B*H*Q bf16
    unsigned short* Tb = qB + (size_t)kB * kH * kQ;               // B*H*Q bf16
    float* part_q = (float*)(Tb + (size_t)kB * kH * kQ);          // B*Q
    float* rowinv = part_q + kB * kQ;                             // B*C
    float* colinv = rowinv + kB * kC;                             // B*Q
    float* ps     = colinv + kB * kQ;                             // B*128*Q
    size_t need = (size_t)((char*)(ps + (size_t)kB * kColChunks * kQ) - (char*)d_ws);
    if (ws_size < need) return;

    // d_out scratch (consumed before k_out_mfma writes):
    //   [0 ..)             : Tpart (8 * B*H*Q bf16 = 16.8 MB)
    //   [2N, ..) floats    : qT (B*Q*H bf16)
    const size_t N = (size_t)kB * kH * kC;
    unsigned short* Tpart = (unsigned short*)out;
    unsigned short* qT    = (unsigned short*)(out + 2 * N);

    k_prep_q<<<dim3(kQ / 64, kB), 256, 0, stream>>>(q, w_q, qT, qB, part_q);
    k_Ssoft<<<dim3(kC / 64, kB), 256, 0, stream>>>(ctx, qT, w_c, w_cq, part_q, bias,
                                                   qmask, cmask, Eb, rowinv, ps);
    k_colZ<<<kB * kQ / 256, 256, 0, stream>>>(ps, colinv);
    k_T2_mfma<<<dim3(8, kB), 512, 0, stream>>>(Eb, ctx, cmask, Tpart);
    k_Tred<<<kB * kH * kQ / 256, 256, 0, stream>>>(Tpart, colinv, Tb);
    k_out_mfma<<<dim3(kC / 64, kB), 256, 0, stream>>>(Eb, qB, Tb, ctx, rowinv, out);
}